// Round 6
// baseline (226.033 us; speedup 1.0000x reference)
//
#include <hip/hip_runtime.h>
#include <hip/hip_fp16.h>

// GCN: 100K nodes, 2.5M edges, dims 4 -> 32 -> (32x32 conv x3) -> 3.
// R16: 16-bit quad CSR (QDIV=25000), 4-phase segmented gather, NBLK=512
//      scatter-free build, fp16 g, fp32 accumulate.  [219 us]
// R19: hierarchical wave-shuffle scans in build.  [215.7]
// R20: half CSR -> 219. REVERTED (1.6MB per-quad L2 hot set load-bearing).
// R21: build memory-path fixes (LDS-staged csr16 flush, int4 run-copy,
//      ei cached in LDS).  [205.2, best]
// R22: gather memory-level-parallelism push (concurrency-bound theory:
//      ~9.3 cyc/edge >> all throughput floors => outstanding-miss limited).
//      (a) cooperative index load: lane sub reads csr16[k+sub], shared via
//          __shfl(.,j,4) — vmem instrs per 4-batch 8 -> 5 (4-group is
//          exec-coherent so the shfl is always safe).
//      (b) t[32] epilogue folded (activation per-k) — ~30 VGPR off peak.
//      (c) __launch_bounds__(256,5) on gather kernels (5 waves/SIMD target).
//      Build kernels byte-identical to R21.

constexpr int N_NODES = 100000;
constexpr int N_EDGES = 2500000;
constexpr int QDIV    = 25000;                             // src quad divisor
constexpr int BUCKET  = 256;
constexpr int NBUCK   = (N_NODES + BUCKET - 1) / BUCKET;   // 391
constexpr int NBLK    = 512;                               // build blocks
constexpr int CHUNK   = (N_EDGES + NBLK - 1) / NBLK;       // 4883
constexpr int SCAP    = 8192;                              // sortdeg LDS stage cap
constexpr int PERLANE = NBLK / 64;                         // 8

// ---- build K1: per-block LDS counting sort by bucket; contiguous write ----
__global__ __launch_bounds__(256) void k_binfill(const int* __restrict__ ei,
                                                 int* __restrict__ binned,
                                                 int* __restrict__ blkbin,
                                                 int* __restrict__ locoff) {
    __shared__ int cnt[NBUCK];
    __shared__ int cur[NBUCK];
    __shared__ int wsum[4];
    __shared__ int stage[CHUNK];
    __shared__ int payload[CHUNK];               // (src<<8)|dst_low8
    __shared__ unsigned short binv[CHUNK];       // dst>>8 (bucket id, <512)
    int tid = threadIdx.x;
    int blk = blockIdx.x;
    int beg = blk * CHUNK;
    int end = min(beg + CHUNK, N_EDGES);
    int m = end - beg;

    for (int i = tid; i < NBUCK; i += 256) cnt[i] = 0;
    __syncthreads();
    // pass 1: histogram + cache payload/bin in LDS (no global re-read later)
    for (int e = beg + tid; e < end; e += 256) {
        int sv = ei[e];
        int d  = ei[N_EDGES + e];
        int bin = d >> 8;
        atomicAdd(&cnt[bin], 1);
        int i = e - beg;
        payload[i] = (sv << 8) | (d & 255);
        binv[i] = (unsigned short)bin;
    }
    __syncthreads();

    // hierarchical shfl scan over 512 slots (2 per thread), 1 barrier.
    int c0 = (2 * tid     < NBUCK) ? cnt[2 * tid]     : 0;
    int c1 = (2 * tid + 1 < NBUCK) ? cnt[2 * tid + 1] : 0;
    int s  = c0 + c1;
    int incl = s;
#pragma unroll
    for (int o = 1; o < 64; o <<= 1) {
        int tm = __shfl_up(incl, o);
        if ((tid & 63) >= o) incl += tm;
    }
    if ((tid & 63) == 63) wsum[tid >> 6] = incl;
    __syncthreads();
    int wexcl = 0;
#pragma unroll
    for (int wi = 0; wi < 4; ++wi) wexcl += (wi < (tid >> 6)) ? wsum[wi] : 0;
    int texcl = wexcl + incl - s;              // exclusive prefix at slot 2*tid
    {
        int i = 2 * tid;
        if (i < NBUCK) {
            cur[i] = texcl;
            blkbin[i * NBLK + blk] = c0;
            locoff[blk * NBUCK + i] = beg + texcl;
        }
        i = 2 * tid + 1;
        if (i < NBUCK) {
            int e1 = texcl + c0;
            cur[i] = e1;
            blkbin[i * NBLK + blk] = c1;
            locoff[blk * NBUCK + i] = beg + e1;
        }
    }
    __syncthreads();

    // pass 2: scatter within LDS from the cached payload
    for (int i = tid; i < m; i += 256) {
        int pos = atomicAdd(&cur[binv[i]], 1);
        stage[pos] = payload[i];
    }
    __syncthreads();
    for (int i = tid; i < m; i += 256) binned[beg + i] = stage[i];  // coalesced
}

// ---- build K2: per-bin total + per-bin run-placement prefix (one wave/bin) ----
__global__ __launch_bounds__(256) void k_binwave(const int* __restrict__ blkbin,
                                                 int* __restrict__ bintot,
                                                 int* __restrict__ blkpos) {
    int w = threadIdx.x >> 6, lane = threadIdx.x & 63;
    int bin = blockIdx.x * 4 + w;
    if (bin >= NBUCK) return;
    int v[PERLANE];
#pragma unroll
    for (int i = 0; i < PERLANE; ++i) v[i] = blkbin[bin * NBLK + lane * PERLANE + i];
    int mysum = 0;
#pragma unroll
    for (int i = 0; i < PERLANE; ++i) mysum += v[i];
    int pre = mysum;
#pragma unroll
    for (int o = 1; o < 64; o <<= 1) {
        int t = __shfl_up(pre, o);
        if (lane >= o) pre += t;
    }
    int excl = pre - mysum;
    int run = excl;
#pragma unroll
    for (int i = 0; i < PERLANE; ++i) {
        blkpos[bin * NBLK + lane * PERLANE + i] = run;
        run += v[i];
    }
    if (lane == 63) bintot[bin] = pre;
}

// ---- build K3: per-bucket 1024-key sort (dst_local*4 + src_quad) ----
// Emits ushort csr (src - quad*QDIV) via LDS staging + coalesced flush.
__global__ __launch_bounds__(512) void k_sortdeg(const int* __restrict__ binned,
                                                 const int* __restrict__ blkbin,
                                                 const int* __restrict__ blkpos,
                                                 const int* __restrict__ locoff,
                                                 const int* __restrict__ bintot,
                                                 unsigned short* __restrict__ csr16,
                                                 int* __restrict__ rowseg,
                                                 float* __restrict__ dinv) {
    __shared__ int stage[SCAP];          // 32 KB
    __shared__ unsigned short outs[SCAP];// 16 KB (csr16 staging)
    __shared__ int runlen[NBLK];         // 2 KB
    __shared__ int runpos[NBLK];         // 2 KB
    __shared__ int cnt[1024];            // 4 KB
    __shared__ int sc[1024];             // 4 KB
    __shared__ int cur[1024];            // 4 KB
    __shared__ int wred[8];
    __shared__ int wtot[8];
    int t = threadIdx.x;
    int b = blockIdx.x;

    // bucket offset via wave-reduce (1 barrier)
    int part = 0;
    for (int i = t; i < b; i += 512) part += bintot[i];
#pragma unroll
    for (int o = 32; o > 0; o >>= 1) part += __shfl_xor(part, o);
    if ((t & 63) == 0) wred[t >> 6] = part;

    if (t < NBLK) {
        runlen[t] = blkbin[b * NBLK + t];
        runpos[t] = blkpos[b * NBLK + t];
    }
    cnt[t] = 0; cnt[t + 512] = 0;
    __syncthreads();

    int beg = 0;
#pragma unroll
    for (int wi = 0; wi < 8; ++wi) beg += wred[wi];
    int end = beg + bintot[b];
    int total = end - beg;
    bool fits = (total <= SCAP);

    if (fits) {
        // run-copy: head-align then int4 vector reads of binned
        for (int blk = t; blk < NBLK; blk += 512) {
            int len = runlen[blk];
            int srcp = locoff[blk * NBUCK + b];
            int dstp = runpos[blk];
            int i = 0;
            while (i < len && ((srcp + i) & 3)) { stage[dstp + i] = binned[srcp + i]; ++i; }
            for (; i + 3 < len; i += 4) {
                int4 v = *(const int4*)(binned + srcp + i);
                stage[dstp + i]     = v.x;
                stage[dstp + i + 1] = v.y;
                stage[dstp + i + 2] = v.z;
                stage[dstp + i + 3] = v.w;
            }
            for (; i < len; ++i) stage[dstp + i] = binned[srcp + i];
        }
        __syncthreads();
        for (int k = t; k < total; k += 512) {
            int p = stage[k];
            int key = ((p & 255) << 2) | ((p >> 8) / QDIV);
            atomicAdd(&cnt[key], 1);
        }
    } else {   // overflow fallback (statistically never)
        for (int blk = t; blk < NBLK; blk += 512) {
            int len = runlen[blk];
            int srcp = locoff[blk * NBUCK + b];
            for (int i = 0; i < len; ++i) {
                int p = binned[srcp + i];
                int key = ((p & 255) << 2) | ((p >> 8) / QDIV);
                atomicAdd(&cnt[key], 1);
            }
        }
    }
    __syncthreads();

    // 1024-key exclusive scan via hierarchical shfl (2 barriers)
    int c0 = cnt[2 * t], c1 = cnt[2 * t + 1];
    int s = c0 + c1;
    int incl = s;
#pragma unroll
    for (int o = 1; o < 64; o <<= 1) {
        int tm = __shfl_up(incl, o);
        if ((t & 63) >= o) incl += tm;
    }
    if ((t & 63) == 63) wtot[t >> 6] = incl;
    __syncthreads();
    int wexcl = 0;
#pragma unroll
    for (int wi = 0; wi < 8; ++wi) wexcl += (wi < (t >> 6)) ? wtot[wi] : 0;
    int texcl = wexcl + incl - s;              // exclusive prefix at slot 2t
    sc[2 * t]     = texcl + c0;                // inclusive values (downstream
    sc[2 * t + 1] = texcl + s;                 //   needs sc[k+3])
    __syncthreads();

#pragma unroll
    for (int slot = 0; slot < 2; ++slot) {
        int k = 2 * t + slot;
        int excl = (slot == 0) ? texcl : (texcl + c0);
        cur[k] = excl;
        int dl = k >> 2, q = k & 3;
        int n = b * BUCKET + dl;
        if (n < N_NODES) {
            rowseg[n * 4 + q] = beg + excl;
            if (q == 0) {
                int deg = sc[k + 3] - excl;          // sum of the 4 quads
                dinv[n] = rsqrtf((float)(deg + 1));  // +1 self-loop
            }
        }
    }
    if (b == NBUCK - 1 && t == 0) rowseg[(size_t)N_NODES * 4] = end;  // sentinel
    __syncthreads();

    if (fits) {
        for (int k = t; k < total; k += 512) {
            int p = stage[k];
            int src = p >> 8;
            int q = src / QDIV;
            int key = ((p & 255) << 2) | q;
            int pos = atomicAdd(&cur[key], 1);
            outs[pos] = (unsigned short)(src - q * QDIV);   // LDS scatter
        }
        __syncthreads();
        for (int k = t; k < total; k += 512)
            csr16[beg + k] = outs[k];                        // coalesced flush
    } else {
        for (int blk = t; blk < NBLK; blk += 512) {
            int len = runlen[blk];
            int srcp = locoff[blk * NBUCK + b];
            for (int i = 0; i < len; ++i) {
                int p = binned[srcp + i];
                int src = p >> 8;
                int q = src / QDIV;
                int key = ((p & 255) << 2) | q;
                int pos = atomicAdd(&cur[key], 1);
                csr16[beg + pos] = (unsigned short)(src - q * QDIV);
            }
        }
    }
}

// ================= dense helpers =================
__device__ inline void store_half8(__half* p, const float* v) {
    __half2 h[4];
#pragma unroll
    for (int i = 0; i < 4; ++i)
        h[i] = __floats2half2_rn(v[2 * i], v[2 * i + 1]);
    *(float4*)p = *(float4*)h;
}

__device__ inline void acc_half8(float* acc, float4 raw) {
    __half2* hp = (__half2*)&raw;
#pragma unroll
    for (int i = 0; i < 4; ++i) {
        float2 f = __half22float2(hp[i]);
        acc[2 * i]     += f.x;
        acc[2 * i + 1] += f.y;
    }
}

// t = relu(x@Wfc1 + bfc1); g = half( dinv * (t@Wc1) )
__global__ __launch_bounds__(256) void k_fc1_conv1(
        const float* __restrict__ x,
        const float* __restrict__ Wfc1, const float* __restrict__ bfc1,
        const float* __restrict__ Wc1, const float* __restrict__ dinv,
        __half* __restrict__ g) {
    __shared__ float  sWf[128];
    __shared__ float  sbf[32];
    __shared__ float4 sW[256];
    if (threadIdx.x < 128) sWf[threadIdx.x] = Wfc1[threadIdx.x];
    if (threadIdx.x < 32)  sbf[threadIdx.x] = bfc1[threadIdx.x];
    sW[threadIdx.x] = ((const float4*)Wc1)[threadIdx.x];
    __syncthreads();

    int n = blockIdx.x * 256 + threadIdx.x;
    if (n >= N_NODES) return;

    float4 xin = *(const float4*)(x + (size_t)n * 4);
    float t[32];
#pragma unroll
    for (int j = 0; j < 32; ++j) {
        float a = fmaf(xin.x, sWf[j], sbf[j]);
        a = fmaf(xin.y, sWf[32 + j], a);
        a = fmaf(xin.z, sWf[64 + j], a);
        a = fmaf(xin.w, sWf[96 + j], a);
        t[j] = fmaxf(a, 0.0f);
    }
    float o[32];
#pragma unroll
    for (int j = 0; j < 32; ++j) o[j] = 0.f;
#pragma unroll
    for (int k = 0; k < 32; ++k) {
        float a = t[k];
#pragma unroll
        for (int q = 0; q < 8; ++q) {
            float4 w = sW[k * 8 + q];
            o[q * 4 + 0] = fmaf(a, w.x, o[q * 4 + 0]);
            o[q * 4 + 1] = fmaf(a, w.y, o[q * 4 + 1]);
            o[q * 4 + 2] = fmaf(a, w.z, o[q * 4 + 2]);
            o[q * 4 + 3] = fmaf(a, w.w, o[q * 4 + 3]);
        }
    }
    float dv = dinv[n];
#pragma unroll
    for (int j = 0; j < 32; ++j) o[j] *= dv;
    __half* gp = g + (size_t)n * 32;
    store_half8(gp,      o);
    store_half8(gp + 8,  o + 8);
    store_half8(gp + 16, o + 16);
    store_half8(gp + 24, o + 24);
}

// ---- edge-segment accumulate over ushort csr: src = base + off ----
// R22: cooperative index load. The 4 sub-lanes of a node are exec-coherent
// (same segment, same k), so lane sub loads csr16[k+sub] and the group
// shares via __shfl(.,j,4): 1 vmem instr instead of 4 per batch.
__device__ inline void gather_seg(int beg, int end, int base,
                                  const unsigned short* __restrict__ csr16,
                                  const __half* __restrict__ gin, int sub, float* acc) {
    int k = beg;
    int stop = beg + ((end - beg) & ~3);
    if (k < stop) {
        int idx = csr16[k + sub];
        int s0 = base + __shfl(idx, 0, 4);
        int s1 = base + __shfl(idx, 1, 4);
        int s2 = base + __shfl(idx, 2, 4);
        int s3 = base + __shfl(idx, 3, 4);
        k += 4;
        while (k < stop) {
            float4 r0 = *(const float4*)(gin + (size_t)s0 * 32 + sub * 8);
            float4 r1 = *(const float4*)(gin + (size_t)s1 * 32 + sub * 8);
            float4 r2 = *(const float4*)(gin + (size_t)s2 * 32 + sub * 8);
            float4 r3 = *(const float4*)(gin + (size_t)s3 * 32 + sub * 8);
            int idx2 = csr16[k + sub];             // next-batch prefetch
            acc_half8(acc, r0); acc_half8(acc, r1);
            acc_half8(acc, r2); acc_half8(acc, r3);
            s0 = base + __shfl(idx2, 0, 4);
            s1 = base + __shfl(idx2, 1, 4);
            s2 = base + __shfl(idx2, 2, 4);
            s3 = base + __shfl(idx2, 3, 4);
            k += 4;
        }
        float4 r0 = *(const float4*)(gin + (size_t)s0 * 32 + sub * 8);
        float4 r1 = *(const float4*)(gin + (size_t)s1 * 32 + sub * 8);
        float4 r2 = *(const float4*)(gin + (size_t)s2 * 32 + sub * 8);
        float4 r3 = *(const float4*)(gin + (size_t)s3 * 32 + sub * 8);
        acc_half8(acc, r0); acc_half8(acc, r1);
        acc_half8(acc, r2); acc_half8(acc, r3);
    }
    for (; k < end; ++k) {
        int s = base + csr16[k];
        float4 r = *(const float4*)(gin + (size_t)s * 32 + sub * 8);
        acc_half8(acc, r);
    }
}

// ---- 4-phase soft gather + mid MLP: 4 threads/node, 64 nodes/block ----
// Per-segment calls act as wave-level phase barriers (SIMT lockstep).
__global__ __launch_bounds__(256, 5) void k_gather_mid(
        const int* __restrict__ rowseg,
        const unsigned short* __restrict__ csr16, const __half* __restrict__ gin,
        const float* __restrict__ dinv,
        const float* __restrict__ b, const float* __restrict__ W,
        __half* __restrict__ gout) {
    __shared__ float sS[64 * 33];
    __shared__ float sW[1024];
    __shared__ float sb[32];
    for (int i = threadIdx.x; i < 1024; i += 256) sW[i] = W[i];
    if (threadIdx.x < 32) sb[threadIdx.x] = b[threadIdx.x];

    int nl = threadIdx.x >> 2;
    int sub = threadIdx.x & 3;
    int n = blockIdx.x * 64 + nl;
    float acc[8];
    if (n < N_NODES) {
        float4 self = *(const float4*)(gin + (size_t)n * 32 + sub * 8);
        {
            __half2* hp = (__half2*)&self;
#pragma unroll
            for (int i = 0; i < 4; ++i) {
                float2 f = __half22float2(hp[i]);
                acc[2 * i] = f.x;
                acc[2 * i + 1] = f.y;
            }
        }
        int4 seg = *(const int4*)(rowseg + (size_t)n * 4);
        int segend = rowseg[(size_t)n * 4 + 4];          // next start / sentinel
        gather_seg(seg.x, seg.y, 0,         csr16, gin, sub, acc);   // quad 0
        gather_seg(seg.y, seg.z, QDIV,      csr16, gin, sub, acc);   // quad 1
        gather_seg(seg.z, seg.w, 2 * QDIV,  csr16, gin, sub, acc);   // quad 2
        gather_seg(seg.w, segend, 3 * QDIV, csr16, gin, sub, acc);   // quad 3
#pragma unroll
        for (int i = 0; i < 8; ++i) sS[nl * 33 + sub * 8 + i] = acc[i];
    }
    __syncthreads();

    if (n >= N_NODES) return;
    float dv = dinv[n];
    // R22: activation folded per-k (no t[32] array -> lower VGPR peak).
    float o[8];
#pragma unroll
    for (int j = 0; j < 8; ++j) o[j] = 0.f;
#pragma unroll
    for (int kk = 0; kk < 32; ++kk) {
        float a = fmaxf(fmaf(dv, sS[nl * 33 + kk], sb[kk]), 0.0f);
#pragma unroll
        for (int j = 0; j < 8; ++j)
            o[j] = fmaf(a, sW[kk * 32 + sub * 8 + j], o[j]);
    }
#pragma unroll
    for (int j = 0; j < 8; ++j) o[j] *= dv;
    store_half8(gout + (size_t)n * 32 + sub * 8, o);
}

// ---- 4-phase soft gather + final layer ----
__global__ __launch_bounds__(256, 5) void k_gather_out(
        const int* __restrict__ rowseg,
        const unsigned short* __restrict__ csr16, const __half* __restrict__ gin,
        const float* __restrict__ dinv,
        const float* __restrict__ bc3, const float* __restrict__ Wfc2,
        const float* __restrict__ bfc2, float* __restrict__ out) {
    __shared__ float sS[64 * 33];
    __shared__ float sW[96];
    __shared__ float sb[32];
    __shared__ float sb2[3];
    if (threadIdx.x < 96) sW[threadIdx.x] = Wfc2[threadIdx.x];
    if (threadIdx.x < 32) sb[threadIdx.x] = bc3[threadIdx.x];
    if (threadIdx.x < 3)  sb2[threadIdx.x] = bfc2[threadIdx.x];

    int nl = threadIdx.x >> 2;
    int sub = threadIdx.x & 3;
    int n = blockIdx.x * 64 + nl;
    float acc[8];
    if (n < N_NODES) {
        float4 self = *(const float4*)(gin + (size_t)n * 32 + sub * 8);
        {
            __half2* hp = (__half2*)&self;
#pragma unroll
            for (int i = 0; i < 4; ++i) {
                float2 f = __half22float2(hp[i]);
                acc[2 * i] = f.x;
                acc[2 * i + 1] = f.y;
            }
        }
        int4 seg = *(const int4*)(rowseg + (size_t)n * 4);
        int segend = rowseg[(size_t)n * 4 + 4];
        gather_seg(seg.x, seg.y, 0,         csr16, gin, sub, acc);
        gather_seg(seg.y, seg.z, QDIV,      csr16, gin, sub, acc);
        gather_seg(seg.z, seg.w, 2 * QDIV,  csr16, gin, sub, acc);
        gather_seg(seg.w, segend, 3 * QDIV, csr16, gin, sub, acc);
#pragma unroll
        for (int i = 0; i < 8; ++i) sS[nl * 33 + sub * 8 + i] = acc[i];
    }
    __syncthreads();

    if (n >= N_NODES || sub != 0) return;
    float dv = dinv[n];
    // R22: t[32] folded (activation computed per-k).
    float o0 = sb2[0], o1 = sb2[1], o2 = sb2[2];
#pragma unroll
    for (int kk = 0; kk < 32; ++kk) {
        float a = fmaxf(fmaf(dv, sS[nl * 33 + kk], sb[kk]), 0.0f);
        o0 = fmaf(a, sW[kk * 3 + 0], o0);
        o1 = fmaf(a, sW[kk * 3 + 1], o1);
        o2 = fmaf(a, sW[kk * 3 + 2], o2);
    }
    out[(size_t)n * 3 + 0] = o0;
    out[(size_t)n * 3 + 1] = o1;
    out[(size_t)n * 3 + 2] = o2;
}

extern "C" void kernel_launch(void* const* d_in, const int* in_sizes, int n_in,
                              void* d_out, int out_size, void* d_ws, size_t ws_size,
                              hipStream_t stream) {
    const float* x    = (const float*)d_in[0];
    const int*   ei   = (const int*)d_in[1];
    const float* Wfc1 = (const float*)d_in[2];
    const float* bfc1 = (const float*)d_in[3];
    const float* Wc1  = (const float*)d_in[4];
    const float* bc1  = (const float*)d_in[5];
    const float* Wc2  = (const float*)d_in[6];
    const float* bc2  = (const float*)d_in[7];
    const float* Wc3  = (const float*)d_in[8];
    const float* bc3  = (const float*)d_in[9];
    const float* Wfc2 = (const float*)d_in[10];
    const float* bfc2 = (const float*)d_in[11];
    float* out = (float*)d_out;

    char* ws = (char*)d_ws;
    const size_t grow = (size_t)N_NODES * 32 * sizeof(__half);   // 6.4 MB
    size_t off = 0;
    __half* gA     = (__half*)(ws + off); off += grow;
    __half* gB     = (__half*)(ws + off); off += grow;
    int*   binned  = (int*)  (ws + off); off += (size_t)NBLK * CHUNK * sizeof(int);
    unsigned short* csr16 = (unsigned short*)(ws + off);
    off += ((size_t)N_EDGES + 8) * sizeof(unsigned short);
    float* dinv    = (float*)(ws + off); off += (size_t)N_NODES * sizeof(float);
    int*   rowseg  = (int*)  (ws + off); off += ((size_t)N_NODES * 4 + 16) * sizeof(int);
    int*   blkbin  = (int*)  (ws + off); off += (size_t)NBUCK * NBLK * sizeof(int);
    int*   blkpos  = (int*)  (ws + off); off += (size_t)NBUCK * NBLK * sizeof(int);
    int*   locoff  = (int*)  (ws + off); off += (size_t)NBLK * NBUCK * sizeof(int);
    int*   bintot  = (int*)  (ws + off); off += (size_t)NBUCK * sizeof(int);

    const int nb_wave = (NBUCK + 3) / 4;              // 98
    const int nb_n = (N_NODES + 255) / 256;           // 391
    const int nb_f = (N_NODES * 4 + 255) / 256;       // 1563 (4 thr/node)

    k_binfill<<<NBLK, 256, 0, stream>>>(ei, binned, blkbin, locoff);
    k_binwave<<<nb_wave, 256, 0, stream>>>(blkbin, bintot, blkpos);
    k_sortdeg<<<NBUCK, 512, 0, stream>>>(binned, blkbin, blkpos, locoff, bintot,
                                         csr16, rowseg, dinv);

    k_fc1_conv1<<<nb_n, 256, 0, stream>>>(x, Wfc1, bfc1, Wc1, dinv, gA);
    k_gather_mid<<<nb_f, 256, 0, stream>>>(rowseg, csr16, gA, dinv, bc1, Wc2, gB);
    k_gather_mid<<<nb_f, 256, 0, stream>>>(rowseg, csr16, gB, dinv, bc2, Wc3, gA);
    k_gather_out<<<nb_f, 256, 0, stream>>>(rowseg, csr16, gA, dinv, bc3, Wfc2, bfc2, out);
}

// Round 7
// 198.827 us; speedup vs baseline: 1.1368x; 1.1368x over previous
//
#include <hip/hip_runtime.h>
#include <hip/hip_fp16.h>

// GCN: 100K nodes, 2.5M edges, dims 4 -> 32 -> (32x32 conv x3) -> 3.
// R16: 16-bit quad CSR (QDIV=25000), 4-phase segmented gather.  [219 us]
// R19: wave-shuffle scans in build.  [215.7]
// R20: half CSR -> 219. REVERTED (1.6MB per-quad L2 hot set load-bearing).
// R21: build memory-path fixes (LDS-staged csr16 flush, int4 run-copy,
//      ei cached in LDS).  [205.2, best]
// R22: shfl coop-index + folded epilogue -> 226. REVERTED. Attribution:
//      folded t[32] epilogue costs ~8us (present in ALL of R17/R18/R22's
//      ~226-227 results); shfl latency on addr path cost the rest. The
//      R16-form gather loop has survived 4 attack attempts: local optimum.
// R23: build-only round, gathers byte-identical to R21:
//      (a) k_binwave ABSORBED into k_sortdeg: runpos = in-block shfl scan
//          of runlen; bucket base = sum(locoff[blk][b]) - SUMOFF (locoff
//          rows were already being read for run-copy; now hoisted to LDS
//          and reused). Removes a launch, the O(b) bintot loop, ~2.4MB of
//          blkbin/blkpos traffic, and scattered locoff re-reads.
//      (b) k_binfill pass-1 reads ei via int4 (vmem instrs /4 on 20MB).

constexpr int N_NODES = 100000;
constexpr int N_EDGES = 2500000;
constexpr int QDIV    = 25000;                             // src quad divisor
constexpr int BUCKET  = 256;
constexpr int NBUCK   = (N_NODES + BUCKET - 1) / BUCKET;   // 391
constexpr int NBLK    = 512;                               // build blocks
constexpr int CHUNK   = (N_EDGES + NBLK - 1) / NBLK;       // 4883
constexpr int SCAP    = 8192;                              // sortdeg LDS stage cap
// sum over blk of blk*CHUNK (base offsets embedded in locoff)
constexpr int SUMOFF  = CHUNK * ((NBLK * (NBLK - 1)) / 2); // 638,774,528

// ---- build K1: per-block LDS counting sort by bucket; contiguous write ----
__global__ __launch_bounds__(256) void k_binfill(const int* __restrict__ ei,
                                                 int* __restrict__ binned,
                                                 int* __restrict__ blkbin,
                                                 int* __restrict__ locoff) {
    __shared__ int cnt[NBUCK];
    __shared__ int cur[NBUCK];
    __shared__ int wsum[4];
    __shared__ int stage[CHUNK];
    __shared__ int payload[CHUNK];               // (src<<8)|dst_low8
    __shared__ unsigned short binv[CHUNK];       // dst>>8 (bucket id)
    int tid = threadIdx.x;
    int blk = blockIdx.x;
    int beg = blk * CHUNK;
    int end = min(beg + CHUNK, N_EDGES);
    int m = end - beg;

    for (int i = tid; i < NBUCK; i += 256) cnt[i] = 0;
    __syncthreads();

    // pass 1 (R23: int4-vectorized): head / body / tail
    int a0 = min((beg + 3) & ~3, end);
    int a1 = (end > a0) ? (a0 + ((end - a0) & ~3)) : a0;
    if (tid < a0 - beg) {
        int e = beg + tid;
        int sv = ei[e], d = ei[N_EDGES + e];
        int bin = d >> 8;
        atomicAdd(&cnt[bin], 1);
        payload[e - beg] = (sv << 8) | (d & 255);
        binv[e - beg] = (unsigned short)bin;
    }
    for (int e = a0 + tid * 4; e < a1; e += 1024) {
        int4 s4 = *(const int4*)(ei + e);
        int4 d4 = *(const int4*)(ei + N_EDGES + e);
        int i = e - beg;
        int b0 = d4.x >> 8, b1 = d4.y >> 8, b2 = d4.z >> 8, b3 = d4.w >> 8;
        atomicAdd(&cnt[b0], 1); atomicAdd(&cnt[b1], 1);
        atomicAdd(&cnt[b2], 1); atomicAdd(&cnt[b3], 1);
        payload[i]     = (s4.x << 8) | (d4.x & 255);
        payload[i + 1] = (s4.y << 8) | (d4.y & 255);
        payload[i + 2] = (s4.z << 8) | (d4.z & 255);
        payload[i + 3] = (s4.w << 8) | (d4.w & 255);
        binv[i]     = (unsigned short)b0;
        binv[i + 1] = (unsigned short)b1;
        binv[i + 2] = (unsigned short)b2;
        binv[i + 3] = (unsigned short)b3;
    }
    {
        int e = a1 + tid;
        if (e < end) {
            int sv = ei[e], d = ei[N_EDGES + e];
            int bin = d >> 8;
            atomicAdd(&cnt[bin], 1);
            payload[e - beg] = (sv << 8) | (d & 255);
            binv[e - beg] = (unsigned short)bin;
        }
    }
    __syncthreads();

    // hierarchical shfl scan over 512 slots (2 per thread), 1 barrier.
    int c0 = (2 * tid     < NBUCK) ? cnt[2 * tid]     : 0;
    int c1 = (2 * tid + 1 < NBUCK) ? cnt[2 * tid + 1] : 0;
    int s  = c0 + c1;
    int incl = s;
#pragma unroll
    for (int o = 1; o < 64; o <<= 1) {
        int tm = __shfl_up(incl, o);
        if ((tid & 63) >= o) incl += tm;
    }
    if ((tid & 63) == 63) wsum[tid >> 6] = incl;
    __syncthreads();
    int wexcl = 0;
#pragma unroll
    for (int wi = 0; wi < 4; ++wi) wexcl += (wi < (tid >> 6)) ? wsum[wi] : 0;
    int texcl = wexcl + incl - s;              // exclusive prefix at slot 2*tid
    {
        int i = 2 * tid;
        if (i < NBUCK) {
            cur[i] = texcl;
            blkbin[i * NBLK + blk] = c0;
            locoff[blk * NBUCK + i] = beg + texcl;
        }
        i = 2 * tid + 1;
        if (i < NBUCK) {
            int e1 = texcl + c0;
            cur[i] = e1;
            blkbin[i * NBLK + blk] = c1;
            locoff[blk * NBUCK + i] = beg + e1;
        }
    }
    __syncthreads();

    // pass 2: scatter within LDS from the cached payload
    for (int i = tid; i < m; i += 256) {
        int pos = atomicAdd(&cur[binv[i]], 1);
        stage[pos] = payload[i];
    }
    __syncthreads();
    for (int i = tid; i < m; i += 256) binned[beg + i] = stage[i];  // coalesced
}

// ---- build K2: per-bucket 1024-key sort (dst_local*4 + src_quad) ----
// R23: self-contained — computes runpos (scan of runlen) and its bucket
// base offset (sum of locoff column minus SUMOFF) in-block. binwave gone.
__global__ __launch_bounds__(512) void k_sortdeg(const int* __restrict__ binned,
                                                 const int* __restrict__ blkbin,
                                                 const int* __restrict__ locoff,
                                                 unsigned short* __restrict__ csr16,
                                                 int* __restrict__ rowseg,
                                                 float* __restrict__ dinv) {
    __shared__ int stage[SCAP];          // 32 KB
    __shared__ unsigned short outs[SCAP];// 16 KB (csr16 staging)
    __shared__ int runlen[NBLK];         // 2 KB
    __shared__ int runpos[NBLK];         // 2 KB
    __shared__ int loc[NBLK];            // 2 KB (locoff column, reused)
    __shared__ int cnt[1024];            // 4 KB
    __shared__ int sc[1024];             // 4 KB
    __shared__ int cur[1024];            // 4 KB
    __shared__ int wtot[8];
    __shared__ int wloc[8];
    int t = threadIdx.x;
    int b = blockIdx.x;
    int lane = t & 63, w = t >> 6;

    int rl = blkbin[b * NBLK + t];       // NBLK == blockDim == 512
    int lc = locoff[t * NBUCK + b];
    runlen[t] = rl;
    loc[t] = lc;
    cnt[t] = 0; cnt[t + 512] = 0;

    // fused: exclusive scan of runlen (runpos) + reduce of loc (base offset)
    int incl = rl;
#pragma unroll
    for (int o = 1; o < 64; o <<= 1) {
        int tm = __shfl_up(incl, o);
        if (lane >= o) incl += tm;
    }
    int lsum = lc;
#pragma unroll
    for (int o = 32; o > 0; o >>= 1) lsum += __shfl_xor(lsum, o);
    if (lane == 63) wtot[w] = incl;
    if (lane == 0)  wloc[w] = lsum;
    __syncthreads();
    int wexcl = 0, total = 0, locsum = 0;
#pragma unroll
    for (int wi = 0; wi < 8; ++wi) {
        wexcl  += (wi < w) ? wtot[wi] : 0;
        total  += wtot[wi];
        locsum += wloc[wi];
    }
    runpos[t] = wexcl + incl - rl;
    int beg = locsum - SUMOFF;           // #edges in buckets < b
    int end = beg + total;
    bool fits = (total <= SCAP);
    __syncthreads();                     // runpos visible

    if (fits) {
        // run-copy: head-align then int4 vector reads of binned
        for (int blk = t; blk < NBLK; blk += 512) {
            int len = runlen[blk];
            int srcp = loc[blk];
            int dstp = runpos[blk];
            int i = 0;
            while (i < len && ((srcp + i) & 3)) { stage[dstp + i] = binned[srcp + i]; ++i; }
            for (; i + 3 < len; i += 4) {
                int4 v = *(const int4*)(binned + srcp + i);
                stage[dstp + i]     = v.x;
                stage[dstp + i + 1] = v.y;
                stage[dstp + i + 2] = v.z;
                stage[dstp + i + 3] = v.w;
            }
            for (; i < len; ++i) stage[dstp + i] = binned[srcp + i];
        }
        __syncthreads();
        for (int k = t; k < total; k += 512) {
            int p = stage[k];
            int key = ((p & 255) << 2) | ((p >> 8) / QDIV);
            atomicAdd(&cnt[key], 1);
        }
    } else {   // overflow fallback (statistically never)
        for (int blk = t; blk < NBLK; blk += 512) {
            int len = runlen[blk];
            int srcp = loc[blk];
            for (int i = 0; i < len; ++i) {
                int p = binned[srcp + i];
                int key = ((p & 255) << 2) | ((p >> 8) / QDIV);
                atomicAdd(&cnt[key], 1);
            }
        }
    }
    __syncthreads();

    // 1024-key exclusive scan via hierarchical shfl
    int c0 = cnt[2 * t], c1 = cnt[2 * t + 1];
    int s = c0 + c1;
    int incl2 = s;
#pragma unroll
    for (int o = 1; o < 64; o <<= 1) {
        int tm = __shfl_up(incl2, o);
        if (lane >= o) incl2 += tm;
    }
    if (lane == 63) wtot[w] = incl2;
    __syncthreads();
    int wexcl2 = 0;
#pragma unroll
    for (int wi = 0; wi < 8; ++wi) wexcl2 += (wi < w) ? wtot[wi] : 0;
    int texcl = wexcl2 + incl2 - s;            // exclusive prefix at slot 2t
    sc[2 * t]     = texcl + c0;                // inclusive values (downstream
    sc[2 * t + 1] = texcl + s;                 //   needs sc[k+3])
    __syncthreads();

#pragma unroll
    for (int slot = 0; slot < 2; ++slot) {
        int k = 2 * t + slot;
        int excl = (slot == 0) ? texcl : (texcl + c0);
        cur[k] = excl;
        int dl = k >> 2, q = k & 3;
        int n = b * BUCKET + dl;
        if (n < N_NODES) {
            rowseg[n * 4 + q] = beg + excl;
            if (q == 0) {
                int deg = sc[k + 3] - excl;          // sum of the 4 quads
                dinv[n] = rsqrtf((float)(deg + 1));  // +1 self-loop
            }
        }
    }
    if (b == NBUCK - 1 && t == 0) rowseg[(size_t)N_NODES * 4] = end;  // sentinel
    __syncthreads();

    if (fits) {
        for (int k = t; k < total; k += 512) {
            int p = stage[k];
            int src = p >> 8;
            int q = src / QDIV;
            int key = ((p & 255) << 2) | q;
            int pos = atomicAdd(&cur[key], 1);
            outs[pos] = (unsigned short)(src - q * QDIV);   // LDS scatter
        }
        __syncthreads();
        for (int k = t; k < total; k += 512)
            csr16[beg + k] = outs[k];                        // coalesced flush
    } else {
        for (int blk = t; blk < NBLK; blk += 512) {
            int len = runlen[blk];
            int srcp = loc[blk];
            for (int i = 0; i < len; ++i) {
                int p = binned[srcp + i];
                int src = p >> 8;
                int q = src / QDIV;
                int key = ((p & 255) << 2) | q;
                int pos = atomicAdd(&cur[key], 1);
                csr16[beg + pos] = (unsigned short)(src - q * QDIV);
            }
        }
    }
}

// ================= dense helpers =================
__device__ inline void store_half8(__half* p, const float* v) {
    __half2 h[4];
#pragma unroll
    for (int i = 0; i < 4; ++i)
        h[i] = __floats2half2_rn(v[2 * i], v[2 * i + 1]);
    *(float4*)p = *(float4*)h;
}

__device__ inline void acc_half8(float* acc, float4 raw) {
    __half2* hp = (__half2*)&raw;
#pragma unroll
    for (int i = 0; i < 4; ++i) {
        float2 f = __half22float2(hp[i]);
        acc[2 * i]     += f.x;
        acc[2 * i + 1] += f.y;
    }
}

// t = relu(x@Wfc1 + bfc1); g = half( dinv * (t@Wc1) )
__global__ __launch_bounds__(256) void k_fc1_conv1(
        const float* __restrict__ x,
        const float* __restrict__ Wfc1, const float* __restrict__ bfc1,
        const float* __restrict__ Wc1, const float* __restrict__ dinv,
        __half* __restrict__ g) {
    __shared__ float  sWf[128];
    __shared__ float  sbf[32];
    __shared__ float4 sW[256];
    if (threadIdx.x < 128) sWf[threadIdx.x] = Wfc1[threadIdx.x];
    if (threadIdx.x < 32)  sbf[threadIdx.x] = bfc1[threadIdx.x];
    sW[threadIdx.x] = ((const float4*)Wc1)[threadIdx.x];
    __syncthreads();

    int n = blockIdx.x * 256 + threadIdx.x;
    if (n >= N_NODES) return;

    float4 xin = *(const float4*)(x + (size_t)n * 4);
    float t[32];
#pragma unroll
    for (int j = 0; j < 32; ++j) {
        float a = fmaf(xin.x, sWf[j], sbf[j]);
        a = fmaf(xin.y, sWf[32 + j], a);
        a = fmaf(xin.z, sWf[64 + j], a);
        a = fmaf(xin.w, sWf[96 + j], a);
        t[j] = fmaxf(a, 0.0f);
    }
    float o[32];
#pragma unroll
    for (int j = 0; j < 32; ++j) o[j] = 0.f;
#pragma unroll
    for (int k = 0; k < 32; ++k) {
        float a = t[k];
#pragma unroll
        for (int q = 0; q < 8; ++q) {
            float4 w = sW[k * 8 + q];
            o[q * 4 + 0] = fmaf(a, w.x, o[q * 4 + 0]);
            o[q * 4 + 1] = fmaf(a, w.y, o[q * 4 + 1]);
            o[q * 4 + 2] = fmaf(a, w.z, o[q * 4 + 2]);
            o[q * 4 + 3] = fmaf(a, w.w, o[q * 4 + 3]);
        }
    }
    float dv = dinv[n];
#pragma unroll
    for (int j = 0; j < 32; ++j) o[j] *= dv;
    __half* gp = g + (size_t)n * 32;
    store_half8(gp,      o);
    store_half8(gp + 8,  o + 8);
    store_half8(gp + 16, o + 16);
    store_half8(gp + 24, o + 24);
}

// ---- edge-segment accumulate over ushort csr: src = base + off ----
// (exact R16 form: 4-wide pipelined main loop + scalar remainder)
__device__ inline void gather_seg(int beg, int end, int base,
                                  const unsigned short* __restrict__ csr16,
                                  const __half* __restrict__ gin, int sub, float* acc) {
    int k = beg;
    int stop = beg + ((end - beg) & ~3);
    if (k < stop) {
        int s0 = base + csr16[k],     s1 = base + csr16[k + 1];
        int s2 = base + csr16[k + 2], s3 = base + csr16[k + 3];
        k += 4;
        while (k < stop) {
            float4 r0 = *(const float4*)(gin + (size_t)s0 * 32 + sub * 8);
            float4 r1 = *(const float4*)(gin + (size_t)s1 * 32 + sub * 8);
            float4 r2 = *(const float4*)(gin + (size_t)s2 * 32 + sub * 8);
            float4 r3 = *(const float4*)(gin + (size_t)s3 * 32 + sub * 8);
            s0 = base + csr16[k];     s1 = base + csr16[k + 1];
            s2 = base + csr16[k + 2]; s3 = base + csr16[k + 3];
            acc_half8(acc, r0); acc_half8(acc, r1);
            acc_half8(acc, r2); acc_half8(acc, r3);
            k += 4;
        }
        float4 r0 = *(const float4*)(gin + (size_t)s0 * 32 + sub * 8);
        float4 r1 = *(const float4*)(gin + (size_t)s1 * 32 + sub * 8);
        float4 r2 = *(const float4*)(gin + (size_t)s2 * 32 + sub * 8);
        float4 r3 = *(const float4*)(gin + (size_t)s3 * 32 + sub * 8);
        acc_half8(acc, r0); acc_half8(acc, r1);
        acc_half8(acc, r2); acc_half8(acc, r3);
    }
    for (; k < end; ++k) {
        int s = base + csr16[k];
        float4 r = *(const float4*)(gin + (size_t)s * 32 + sub * 8);
        acc_half8(acc, r);
    }
}

// ---- 4-phase soft gather + mid MLP: 4 threads/node, 64 nodes/block ----
// Per-segment calls act as wave-level phase barriers (SIMT lockstep).
__global__ __launch_bounds__(256) void k_gather_mid(
        const int* __restrict__ rowseg,
        const unsigned short* __restrict__ csr16, const __half* __restrict__ gin,
        const float* __restrict__ dinv,
        const float* __restrict__ b, const float* __restrict__ W,
        __half* __restrict__ gout) {
    __shared__ float sS[64 * 33];
    __shared__ float sW[1024];
    __shared__ float sb[32];
    for (int i = threadIdx.x; i < 1024; i += 256) sW[i] = W[i];
    if (threadIdx.x < 32) sb[threadIdx.x] = b[threadIdx.x];

    int nl = threadIdx.x >> 2;
    int sub = threadIdx.x & 3;
    int n = blockIdx.x * 64 + nl;
    float acc[8];
    if (n < N_NODES) {
        float4 self = *(const float4*)(gin + (size_t)n * 32 + sub * 8);
        {
            __half2* hp = (__half2*)&self;
#pragma unroll
            for (int i = 0; i < 4; ++i) {
                float2 f = __half22float2(hp[i]);
                acc[2 * i] = f.x;
                acc[2 * i + 1] = f.y;
            }
        }
        int4 seg = *(const int4*)(rowseg + (size_t)n * 4);
        int segend = rowseg[(size_t)n * 4 + 4];          // next start / sentinel
        gather_seg(seg.x, seg.y, 0,         csr16, gin, sub, acc);   // quad 0
        gather_seg(seg.y, seg.z, QDIV,      csr16, gin, sub, acc);   // quad 1
        gather_seg(seg.z, seg.w, 2 * QDIV,  csr16, gin, sub, acc);   // quad 2
        gather_seg(seg.w, segend, 3 * QDIV, csr16, gin, sub, acc);   // quad 3
#pragma unroll
        for (int i = 0; i < 8; ++i) sS[nl * 33 + sub * 8 + i] = acc[i];
    }
    __syncthreads();

    if (n >= N_NODES) return;
    float dv = dinv[n];
    float t[32];
#pragma unroll
    for (int kk = 0; kk < 32; ++kk)
        t[kk] = fmaxf(fmaf(dv, sS[nl * 33 + kk], sb[kk]), 0.0f);
    float o[8];
#pragma unroll
    for (int j = 0; j < 8; ++j) o[j] = 0.f;
#pragma unroll
    for (int kk = 0; kk < 32; ++kk) {
        float a = t[kk];
#pragma unroll
        for (int j = 0; j < 8; ++j)
            o[j] = fmaf(a, sW[kk * 32 + sub * 8 + j], o[j]);
    }
#pragma unroll
    for (int j = 0; j < 8; ++j) o[j] *= dv;
    store_half8(gout + (size_t)n * 32 + sub * 8, o);
}

// ---- 4-phase soft gather + final layer ----
__global__ __launch_bounds__(256) void k_gather_out(
        const int* __restrict__ rowseg,
        const unsigned short* __restrict__ csr16, const __half* __restrict__ gin,
        const float* __restrict__ dinv,
        const float* __restrict__ bc3, const float* __restrict__ Wfc2,
        const float* __restrict__ bfc2, float* __restrict__ out) {
    __shared__ float sS[64 * 33];
    __shared__ float sW[96];
    __shared__ float sb[32];
    __shared__ float sb2[3];
    if (threadIdx.x < 96) sW[threadIdx.x] = Wfc2[threadIdx.x];
    if (threadIdx.x < 32) sb[threadIdx.x] = bc3[threadIdx.x];
    if (threadIdx.x < 3)  sb2[threadIdx.x] = bfc2[threadIdx.x];

    int nl = threadIdx.x >> 2;
    int sub = threadIdx.x & 3;
    int n = blockIdx.x * 64 + nl;
    float acc[8];
    if (n < N_NODES) {
        float4 self = *(const float4*)(gin + (size_t)n * 32 + sub * 8);
        {
            __half2* hp = (__half2*)&self;
#pragma unroll
            for (int i = 0; i < 4; ++i) {
                float2 f = __half22float2(hp[i]);
                acc[2 * i] = f.x;
                acc[2 * i + 1] = f.y;
            }
        }
        int4 seg = *(const int4*)(rowseg + (size_t)n * 4);
        int segend = rowseg[(size_t)n * 4 + 4];
        gather_seg(seg.x, seg.y, 0,         csr16, gin, sub, acc);
        gather_seg(seg.y, seg.z, QDIV,      csr16, gin, sub, acc);
        gather_seg(seg.z, seg.w, 2 * QDIV,  csr16, gin, sub, acc);
        gather_seg(seg.w, segend, 3 * QDIV, csr16, gin, sub, acc);
#pragma unroll
        for (int i = 0; i < 8; ++i) sS[nl * 33 + sub * 8 + i] = acc[i];
    }
    __syncthreads();

    if (n >= N_NODES || sub != 0) return;
    float dv = dinv[n];
    float t[32];
#pragma unroll
    for (int kk = 0; kk < 32; ++kk)
        t[kk] = fmaxf(fmaf(dv, sS[nl * 33 + kk], sb[kk]), 0.0f);
    float o0 = sb2[0], o1 = sb2[1], o2 = sb2[2];
#pragma unroll
    for (int kk = 0; kk < 32; ++kk) {
        o0 = fmaf(t[kk], sW[kk * 3 + 0], o0);
        o1 = fmaf(t[kk], sW[kk * 3 + 1], o1);
        o2 = fmaf(t[kk], sW[kk * 3 + 2], o2);
    }
    out[(size_t)n * 3 + 0] = o0;
    out[(size_t)n * 3 + 1] = o1;
    out[(size_t)n * 3 + 2] = o2;
}

extern "C" void kernel_launch(void* const* d_in, const int* in_sizes, int n_in,
                              void* d_out, int out_size, void* d_ws, size_t ws_size,
                              hipStream_t stream) {
    const float* x    = (const float*)d_in[0];
    const int*   ei   = (const int*)d_in[1];
    const float* Wfc1 = (const float*)d_in[2];
    const float* bfc1 = (const float*)d_in[3];
    const float* Wc1  = (const float*)d_in[4];
    const float* bc1  = (const float*)d_in[5];
    const float* Wc2  = (const float*)d_in[6];
    const float* bc2  = (const float*)d_in[7];
    const float* Wc3  = (const float*)d_in[8];
    const float* bc3  = (const float*)d_in[9];
    const float* Wfc2 = (const float*)d_in[10];
    const float* bfc2 = (const float*)d_in[11];
    float* out = (float*)d_out;

    char* ws = (char*)d_ws;
    const size_t grow = (size_t)N_NODES * 32 * sizeof(__half);   // 6.4 MB
    size_t off = 0;
    __half* gA     = (__half*)(ws + off); off += grow;
    __half* gB     = (__half*)(ws + off); off += grow;
    int*   binned  = (int*)  (ws + off); off += (size_t)NBLK * CHUNK * sizeof(int);
    unsigned short* csr16 = (unsigned short*)(ws + off);
    off += ((size_t)N_EDGES + 8) * sizeof(unsigned short);
    float* dinv    = (float*)(ws + off); off += (size_t)N_NODES * sizeof(float);
    int*   rowseg  = (int*)  (ws + off); off += ((size_t)N_NODES * 4 + 16) * sizeof(int);
    int*   blkbin  = (int*)  (ws + off); off += (size_t)NBUCK * NBLK * sizeof(int);
    int*   locoff  = (int*)  (ws + off); off += (size_t)NBLK * NBUCK * sizeof(int);

    const int nb_n = (N_NODES + 255) / 256;           // 391
    const int nb_f = (N_NODES * 4 + 255) / 256;       // 1563 (4 thr/node)

    k_binfill<<<NBLK, 256, 0, stream>>>(ei, binned, blkbin, locoff);
    k_sortdeg<<<NBUCK, 512, 0, stream>>>(binned, blkbin, locoff,
                                         csr16, rowseg, dinv);

    k_fc1_conv1<<<nb_n, 256, 0, stream>>>(x, Wfc1, bfc1, Wc1, dinv, gA);
    k_gather_mid<<<nb_f, 256, 0, stream>>>(rowseg, csr16, gA, dinv, bc1, Wc2, gB);
    k_gather_mid<<<nb_f, 256, 0, stream>>>(rowseg, csr16, gB, dinv, bc2, Wc3, gA);
    k_gather_out<<<nb_f, 256, 0, stream>>>(rowseg, csr16, gA, dinv, bc3, Wfc2, bfc2, out);
}

// Round 8
// 193.792 us; speedup vs baseline: 1.1664x; 1.0260x over previous
//
#include <hip/hip_runtime.h>
#include <hip/hip_fp16.h>

// GCN: 100K nodes, 2.5M edges, dims 4 -> 32 -> (32x32 conv x3) -> 3.
// R16: 16-bit quad CSR (QDIV=25000), 4-phase segmented gather.  [219 us]
// R19: wave-shuffle scans in build.  [215.7]
// R21: build memory-path fixes (LDS-staged csr16 flush, int4 run-copy,
//      ei cached in LDS).  [205.2]
// R23: k_binwave absorbed into k_sortdeg (runpos in-block, bucket base from
//      locoff column sum - SUMOFF); int4 ei reads in binfill.  [198.8, best]
// R22 lesson: folded t[32] epilogue costs ~8us; shfl on addr path hurts.
//      Gather loop = local optimum (4 failed attacks), byte-identical here.
// R24: k_fc1_conv1 FUSED into k_sortdeg tail. dinv is block-local (block b
//      owns nodes [b*256,b*256+256)), so fc1+conv1 runs in-block: dinv via
//      LDS (dloc), x read coalesced, weights (5.2KB) loaded once per block.
//      Kills a launch, the dinv global re-read, and overlaps fc1 memory
//      with sortdeg wind-down. 2 threads/node, 16 outputs each.

constexpr int N_NODES = 100000;
constexpr int N_EDGES = 2500000;
constexpr int QDIV    = 25000;                             // src quad divisor
constexpr int BUCKET  = 256;
constexpr int NBUCK   = (N_NODES + BUCKET - 1) / BUCKET;   // 391
constexpr int NBLK    = 512;                               // build blocks
constexpr int CHUNK   = (N_EDGES + NBLK - 1) / NBLK;       // 4883
constexpr int SCAP    = 8192;                              // sortdeg LDS stage cap
// sum over blk of blk*CHUNK (base offsets embedded in locoff)
constexpr int SUMOFF  = CHUNK * ((NBLK * (NBLK - 1)) / 2); // 638,774,528

// ---- build K1: per-block LDS counting sort by bucket; contiguous write ----
__global__ __launch_bounds__(256) void k_binfill(const int* __restrict__ ei,
                                                 int* __restrict__ binned,
                                                 int* __restrict__ blkbin,
                                                 int* __restrict__ locoff) {
    __shared__ int cnt[NBUCK];
    __shared__ int cur[NBUCK];
    __shared__ int wsum[4];
    __shared__ int stage[CHUNK];
    __shared__ int payload[CHUNK];               // (src<<8)|dst_low8
    __shared__ unsigned short binv[CHUNK];       // dst>>8 (bucket id)
    int tid = threadIdx.x;
    int blk = blockIdx.x;
    int beg = blk * CHUNK;
    int end = min(beg + CHUNK, N_EDGES);
    int m = end - beg;

    for (int i = tid; i < NBUCK; i += 256) cnt[i] = 0;
    __syncthreads();

    // pass 1 (int4-vectorized): head / body / tail
    int a0 = min((beg + 3) & ~3, end);
    int a1 = (end > a0) ? (a0 + ((end - a0) & ~3)) : a0;
    if (tid < a0 - beg) {
        int e = beg + tid;
        int sv = ei[e], d = ei[N_EDGES + e];
        int bin = d >> 8;
        atomicAdd(&cnt[bin], 1);
        payload[e - beg] = (sv << 8) | (d & 255);
        binv[e - beg] = (unsigned short)bin;
    }
    for (int e = a0 + tid * 4; e < a1; e += 1024) {
        int4 s4 = *(const int4*)(ei + e);
        int4 d4 = *(const int4*)(ei + N_EDGES + e);
        int i = e - beg;
        int b0 = d4.x >> 8, b1 = d4.y >> 8, b2 = d4.z >> 8, b3 = d4.w >> 8;
        atomicAdd(&cnt[b0], 1); atomicAdd(&cnt[b1], 1);
        atomicAdd(&cnt[b2], 1); atomicAdd(&cnt[b3], 1);
        payload[i]     = (s4.x << 8) | (d4.x & 255);
        payload[i + 1] = (s4.y << 8) | (d4.y & 255);
        payload[i + 2] = (s4.z << 8) | (d4.z & 255);
        payload[i + 3] = (s4.w << 8) | (d4.w & 255);
        binv[i]     = (unsigned short)b0;
        binv[i + 1] = (unsigned short)b1;
        binv[i + 2] = (unsigned short)b2;
        binv[i + 3] = (unsigned short)b3;
    }
    {
        int e = a1 + tid;
        if (e < end) {
            int sv = ei[e], d = ei[N_EDGES + e];
            int bin = d >> 8;
            atomicAdd(&cnt[bin], 1);
            payload[e - beg] = (sv << 8) | (d & 255);
            binv[e - beg] = (unsigned short)bin;
        }
    }
    __syncthreads();

    // hierarchical shfl scan over 512 slots (2 per thread), 1 barrier.
    int c0 = (2 * tid     < NBUCK) ? cnt[2 * tid]     : 0;
    int c1 = (2 * tid + 1 < NBUCK) ? cnt[2 * tid + 1] : 0;
    int s  = c0 + c1;
    int incl = s;
#pragma unroll
    for (int o = 1; o < 64; o <<= 1) {
        int tm = __shfl_up(incl, o);
        if ((tid & 63) >= o) incl += tm;
    }
    if ((tid & 63) == 63) wsum[tid >> 6] = incl;
    __syncthreads();
    int wexcl = 0;
#pragma unroll
    for (int wi = 0; wi < 4; ++wi) wexcl += (wi < (tid >> 6)) ? wsum[wi] : 0;
    int texcl = wexcl + incl - s;              // exclusive prefix at slot 2*tid
    {
        int i = 2 * tid;
        if (i < NBUCK) {
            cur[i] = texcl;
            blkbin[i * NBLK + blk] = c0;
            locoff[blk * NBUCK + i] = beg + texcl;
        }
        i = 2 * tid + 1;
        if (i < NBUCK) {
            int e1 = texcl + c0;
            cur[i] = e1;
            blkbin[i * NBLK + blk] = c1;
            locoff[blk * NBUCK + i] = beg + e1;
        }
    }
    __syncthreads();

    // pass 2: scatter within LDS from the cached payload
    for (int i = tid; i < m; i += 256) {
        int pos = atomicAdd(&cur[binv[i]], 1);
        stage[pos] = payload[i];
    }
    __syncthreads();
    for (int i = tid; i < m; i += 256) binned[beg + i] = stage[i];  // coalesced
}

// ================= dense helpers =================
__device__ inline void store_half8(__half* p, const float* v) {
    __half2 h[4];
#pragma unroll
    for (int i = 0; i < 4; ++i)
        h[i] = __floats2half2_rn(v[2 * i], v[2 * i + 1]);
    *(float4*)p = *(float4*)h;
}

__device__ inline void acc_half8(float* acc, float4 raw) {
    __half2* hp = (__half2*)&raw;
#pragma unroll
    for (int i = 0; i < 4; ++i) {
        float2 f = __half22float2(hp[i]);
        acc[2 * i]     += f.x;
        acc[2 * i + 1] += f.y;
    }
}

// ---- build K2 + fc1: per-bucket 1024-key sort -> csr16, then fc1+conv1
// for the block's own 256 nodes (R24 fusion).
__global__ __launch_bounds__(512) void k_sortdeg(const int* __restrict__ binned,
                                                 const int* __restrict__ blkbin,
                                                 const int* __restrict__ locoff,
                                                 const float* __restrict__ x,
                                                 const float* __restrict__ Wfc1,
                                                 const float* __restrict__ bfc1,
                                                 const float* __restrict__ Wc1,
                                                 unsigned short* __restrict__ csr16,
                                                 int* __restrict__ rowseg,
                                                 float* __restrict__ dinv,
                                                 __half* __restrict__ g) {
    __shared__ int stage[SCAP];          // 32 KB
    __shared__ unsigned short outs[SCAP];// 16 KB (csr16 staging)
    __shared__ int runlen[NBLK];         // 2 KB
    __shared__ int runpos[NBLK];         // 2 KB
    __shared__ int loc[NBLK];            // 2 KB (locoff column, reused)
    __shared__ int cnt[1024];            // 4 KB
    __shared__ int sc[1024];             // 4 KB
    __shared__ int cur[1024];            // 4 KB
    __shared__ int wtot[8];
    __shared__ int wloc[8];
    __shared__ float sWf[128];           // fc1 weights
    __shared__ float sbf[32];
    __shared__ float sWc[1024];
    __shared__ float dloc[BUCKET];       // block-local dinv
    int t = threadIdx.x;
    int b = blockIdx.x;
    int lane = t & 63, w = t >> 6;

    int rl = blkbin[b * NBLK + t];       // NBLK == blockDim == 512
    int lc = locoff[t * NBUCK + b];
    runlen[t] = rl;
    loc[t] = lc;
    cnt[t] = 0; cnt[t + 512] = 0;
    if (t < 128) sWf[t] = Wfc1[t];
    if (t < 32)  sbf[t] = bfc1[t];
    for (int i = t; i < 1024; i += 512) sWc[i] = Wc1[i];

    // fused: exclusive scan of runlen (runpos) + reduce of loc (base offset)
    int incl = rl;
#pragma unroll
    for (int o = 1; o < 64; o <<= 1) {
        int tm = __shfl_up(incl, o);
        if (lane >= o) incl += tm;
    }
    int lsum = lc;
#pragma unroll
    for (int o = 32; o > 0; o >>= 1) lsum += __shfl_xor(lsum, o);
    if (lane == 63) wtot[w] = incl;
    if (lane == 0)  wloc[w] = lsum;
    __syncthreads();
    int wexcl = 0, total = 0, locsum = 0;
#pragma unroll
    for (int wi = 0; wi < 8; ++wi) {
        wexcl  += (wi < w) ? wtot[wi] : 0;
        total  += wtot[wi];
        locsum += wloc[wi];
    }
    runpos[t] = wexcl + incl - rl;
    int beg = locsum - SUMOFF;           // #edges in buckets < b
    int end = beg + total;
    bool fits = (total <= SCAP);
    __syncthreads();                     // runpos visible

    if (fits) {
        // run-copy: head-align then int4 vector reads of binned
        for (int blk = t; blk < NBLK; blk += 512) {
            int len = runlen[blk];
            int srcp = loc[blk];
            int dstp = runpos[blk];
            int i = 0;
            while (i < len && ((srcp + i) & 3)) { stage[dstp + i] = binned[srcp + i]; ++i; }
            for (; i + 3 < len; i += 4) {
                int4 v = *(const int4*)(binned + srcp + i);
                stage[dstp + i]     = v.x;
                stage[dstp + i + 1] = v.y;
                stage[dstp + i + 2] = v.z;
                stage[dstp + i + 3] = v.w;
            }
            for (; i < len; ++i) stage[dstp + i] = binned[srcp + i];
        }
        __syncthreads();
        for (int k = t; k < total; k += 512) {
            int p = stage[k];
            int key = ((p & 255) << 2) | ((p >> 8) / QDIV);
            atomicAdd(&cnt[key], 1);
        }
    } else {   // overflow fallback (statistically never)
        for (int blk = t; blk < NBLK; blk += 512) {
            int len = runlen[blk];
            int srcp = loc[blk];
            for (int i = 0; i < len; ++i) {
                int p = binned[srcp + i];
                int key = ((p & 255) << 2) | ((p >> 8) / QDIV);
                atomicAdd(&cnt[key], 1);
            }
        }
    }
    __syncthreads();

    // 1024-key exclusive scan via hierarchical shfl
    int c0 = cnt[2 * t], c1 = cnt[2 * t + 1];
    int s = c0 + c1;
    int incl2 = s;
#pragma unroll
    for (int o = 1; o < 64; o <<= 1) {
        int tm = __shfl_up(incl2, o);
        if (lane >= o) incl2 += tm;
    }
    if (lane == 63) wtot[w] = incl2;
    __syncthreads();
    int wexcl2 = 0;
#pragma unroll
    for (int wi = 0; wi < 8; ++wi) wexcl2 += (wi < w) ? wtot[wi] : 0;
    int texcl = wexcl2 + incl2 - s;            // exclusive prefix at slot 2t
    sc[2 * t]     = texcl + c0;                // inclusive values (downstream
    sc[2 * t + 1] = texcl + s;                 //   needs sc[k+3])
    __syncthreads();

#pragma unroll
    for (int slot = 0; slot < 2; ++slot) {
        int k = 2 * t + slot;
        int excl = (slot == 0) ? texcl : (texcl + c0);
        cur[k] = excl;
        int dl = k >> 2, q = k & 3;
        int n = b * BUCKET + dl;
        if (n < N_NODES) {
            rowseg[n * 4 + q] = beg + excl;
            if (q == 0) {
                int deg = sc[k + 3] - excl;          // sum of the 4 quads
                float dv = rsqrtf((float)(deg + 1)); // +1 self-loop
                dinv[n] = dv;
                dloc[dl] = dv;                       // R24: block-local copy
            }
        }
    }
    if (b == NBUCK - 1 && t == 0) rowseg[(size_t)N_NODES * 4] = end;  // sentinel
    __syncthreads();

    if (fits) {
        for (int k = t; k < total; k += 512) {
            int p = stage[k];
            int src = p >> 8;
            int q = src / QDIV;
            int key = ((p & 255) << 2) | q;
            int pos = atomicAdd(&cur[key], 1);
            outs[pos] = (unsigned short)(src - q * QDIV);   // LDS scatter
        }
        __syncthreads();
        for (int k = t; k < total; k += 512)
            csr16[beg + k] = outs[k];                        // coalesced flush
    } else {
        for (int blk = t; blk < NBLK; blk += 512) {
            int len = runlen[blk];
            int srcp = loc[blk];
            for (int i = 0; i < len; ++i) {
                int p = binned[srcp + i];
                int src = p >> 8;
                int q = src / QDIV;
                int key = ((p & 255) << 2) | q;
                int pos = atomicAdd(&cur[key], 1);
                csr16[beg + pos] = (unsigned short)(src - q * QDIV);
            }
        }
    }

    // ---- R24 fused fc1+conv1 tail: 2 threads/node, 16 outputs each ----
    // g[n] = dinv[n] * ( relu(x[n]@Wfc1 + bfc1) @ Wc1 ), fp16 store.
    {
        int dl = t >> 1;                 // 0..255
        int half = t & 1;                // low/high 16 outputs
        int n = b * BUCKET + dl;
        if (n < N_NODES) {
            float4 xin = *(const float4*)(x + (size_t)n * 4);
            float o[16];
#pragma unroll
            for (int j = 0; j < 16; ++j) o[j] = 0.f;
#pragma unroll
            for (int k = 0; k < 32; ++k) {
                float a = fmaf(xin.x, sWf[k], sbf[k]);
                a = fmaf(xin.y, sWf[32 + k], a);
                a = fmaf(xin.z, sWf[64 + k], a);
                a = fmaf(xin.w, sWf[96 + k], a);
                a = fmaxf(a, 0.0f);
                const float* wr = &sWc[k * 32 + half * 16];
#pragma unroll
                for (int j = 0; j < 16; ++j) o[j] = fmaf(a, wr[j], o[j]);
            }
            float dv = dloc[dl];
#pragma unroll
            for (int j = 0; j < 16; ++j) o[j] *= dv;
            __half* gp = g + (size_t)n * 32 + half * 16;
            store_half8(gp,     o);
            store_half8(gp + 8, o + 8);
        }
    }
}

// ---- edge-segment accumulate over ushort csr: src = base + off ----
// (exact R16 form: 4-wide pipelined main loop + scalar remainder)
__device__ inline void gather_seg(int beg, int end, int base,
                                  const unsigned short* __restrict__ csr16,
                                  const __half* __restrict__ gin, int sub, float* acc) {
    int k = beg;
    int stop = beg + ((end - beg) & ~3);
    if (k < stop) {
        int s0 = base + csr16[k],     s1 = base + csr16[k + 1];
        int s2 = base + csr16[k + 2], s3 = base + csr16[k + 3];
        k += 4;
        while (k < stop) {
            float4 r0 = *(const float4*)(gin + (size_t)s0 * 32 + sub * 8);
            float4 r1 = *(const float4*)(gin + (size_t)s1 * 32 + sub * 8);
            float4 r2 = *(const float4*)(gin + (size_t)s2 * 32 + sub * 8);
            float4 r3 = *(const float4*)(gin + (size_t)s3 * 32 + sub * 8);
            s0 = base + csr16[k];     s1 = base + csr16[k + 1];
            s2 = base + csr16[k + 2]; s3 = base + csr16[k + 3];
            acc_half8(acc, r0); acc_half8(acc, r1);
            acc_half8(acc, r2); acc_half8(acc, r3);
            k += 4;
        }
        float4 r0 = *(const float4*)(gin + (size_t)s0 * 32 + sub * 8);
        float4 r1 = *(const float4*)(gin + (size_t)s1 * 32 + sub * 8);
        float4 r2 = *(const float4*)(gin + (size_t)s2 * 32 + sub * 8);
        float4 r3 = *(const float4*)(gin + (size_t)s3 * 32 + sub * 8);
        acc_half8(acc, r0); acc_half8(acc, r1);
        acc_half8(acc, r2); acc_half8(acc, r3);
    }
    for (; k < end; ++k) {
        int s = base + csr16[k];
        float4 r = *(const float4*)(gin + (size_t)s * 32 + sub * 8);
        acc_half8(acc, r);
    }
}

// ---- 4-phase soft gather + mid MLP: 4 threads/node, 64 nodes/block ----
// Per-segment calls act as wave-level phase barriers (SIMT lockstep).
__global__ __launch_bounds__(256) void k_gather_mid(
        const int* __restrict__ rowseg,
        const unsigned short* __restrict__ csr16, const __half* __restrict__ gin,
        const float* __restrict__ dinv,
        const float* __restrict__ b, const float* __restrict__ W,
        __half* __restrict__ gout) {
    __shared__ float sS[64 * 33];
    __shared__ float sW[1024];
    __shared__ float sb[32];
    for (int i = threadIdx.x; i < 1024; i += 256) sW[i] = W[i];
    if (threadIdx.x < 32) sb[threadIdx.x] = b[threadIdx.x];

    int nl = threadIdx.x >> 2;
    int sub = threadIdx.x & 3;
    int n = blockIdx.x * 64 + nl;
    float acc[8];
    if (n < N_NODES) {
        float4 self = *(const float4*)(gin + (size_t)n * 32 + sub * 8);
        {
            __half2* hp = (__half2*)&self;
#pragma unroll
            for (int i = 0; i < 4; ++i) {
                float2 f = __half22float2(hp[i]);
                acc[2 * i] = f.x;
                acc[2 * i + 1] = f.y;
            }
        }
        int4 seg = *(const int4*)(rowseg + (size_t)n * 4);
        int segend = rowseg[(size_t)n * 4 + 4];          // next start / sentinel
        gather_seg(seg.x, seg.y, 0,         csr16, gin, sub, acc);   // quad 0
        gather_seg(seg.y, seg.z, QDIV,      csr16, gin, sub, acc);   // quad 1
        gather_seg(seg.z, seg.w, 2 * QDIV,  csr16, gin, sub, acc);   // quad 2
        gather_seg(seg.w, segend, 3 * QDIV, csr16, gin, sub, acc);   // quad 3
#pragma unroll
        for (int i = 0; i < 8; ++i) sS[nl * 33 + sub * 8 + i] = acc[i];
    }
    __syncthreads();

    if (n >= N_NODES) return;
    float dv = dinv[n];
    float t[32];
#pragma unroll
    for (int kk = 0; kk < 32; ++kk)
        t[kk] = fmaxf(fmaf(dv, sS[nl * 33 + kk], sb[kk]), 0.0f);
    float o[8];
#pragma unroll
    for (int j = 0; j < 8; ++j) o[j] = 0.f;
#pragma unroll
    for (int kk = 0; kk < 32; ++kk) {
        float a = t[kk];
#pragma unroll
        for (int j = 0; j < 8; ++j)
            o[j] = fmaf(a, sW[kk * 32 + sub * 8 + j], o[j]);
    }
#pragma unroll
    for (int j = 0; j < 8; ++j) o[j] *= dv;
    store_half8(gout + (size_t)n * 32 + sub * 8, o);
}

// ---- 4-phase soft gather + final layer ----
__global__ __launch_bounds__(256) void k_gather_out(
        const int* __restrict__ rowseg,
        const unsigned short* __restrict__ csr16, const __half* __restrict__ gin,
        const float* __restrict__ dinv,
        const float* __restrict__ bc3, const float* __restrict__ Wfc2,
        const float* __restrict__ bfc2, float* __restrict__ out) {
    __shared__ float sS[64 * 33];
    __shared__ float sW[96];
    __shared__ float sb[32];
    __shared__ float sb2[3];
    if (threadIdx.x < 96) sW[threadIdx.x] = Wfc2[threadIdx.x];
    if (threadIdx.x < 32) sb[threadIdx.x] = bc3[threadIdx.x];
    if (threadIdx.x < 3)  sb2[threadIdx.x] = bfc2[threadIdx.x];

    int nl = threadIdx.x >> 2;
    int sub = threadIdx.x & 3;
    int n = blockIdx.x * 64 + nl;
    float acc[8];
    if (n < N_NODES) {
        float4 self = *(const float4*)(gin + (size_t)n * 32 + sub * 8);
        {
            __half2* hp = (__half2*)&self;
#pragma unroll
            for (int i = 0; i < 4; ++i) {
                float2 f = __half22float2(hp[i]);
                acc[2 * i] = f.x;
                acc[2 * i + 1] = f.y;
            }
        }
        int4 seg = *(const int4*)(rowseg + (size_t)n * 4);
        int segend = rowseg[(size_t)n * 4 + 4];
        gather_seg(seg.x, seg.y, 0,         csr16, gin, sub, acc);
        gather_seg(seg.y, seg.z, QDIV,      csr16, gin, sub, acc);
        gather_seg(seg.z, seg.w, 2 * QDIV,  csr16, gin, sub, acc);
        gather_seg(seg.w, segend, 3 * QDIV, csr16, gin, sub, acc);
#pragma unroll
        for (int i = 0; i < 8; ++i) sS[nl * 33 + sub * 8 + i] = acc[i];
    }
    __syncthreads();

    if (n >= N_NODES || sub != 0) return;
    float dv = dinv[n];
    float t[32];
#pragma unroll
    for (int kk = 0; kk < 32; ++kk)
        t[kk] = fmaxf(fmaf(dv, sS[nl * 33 + kk], sb[kk]), 0.0f);
    float o0 = sb2[0], o1 = sb2[1], o2 = sb2[2];
#pragma unroll
    for (int kk = 0; kk < 32; ++kk) {
        o0 = fmaf(t[kk], sW[kk * 3 + 0], o0);
        o1 = fmaf(t[kk], sW[kk * 3 + 1], o1);
        o2 = fmaf(t[kk], sW[kk * 3 + 2], o2);
    }
    out[(size_t)n * 3 + 0] = o0;
    out[(size_t)n * 3 + 1] = o1;
    out[(size_t)n * 3 + 2] = o2;
}

extern "C" void kernel_launch(void* const* d_in, const int* in_sizes, int n_in,
                              void* d_out, int out_size, void* d_ws, size_t ws_size,
                              hipStream_t stream) {
    const float* x    = (const float*)d_in[0];
    const int*   ei   = (const int*)d_in[1];
    const float* Wfc1 = (const float*)d_in[2];
    const float* bfc1 = (const float*)d_in[3];
    const float* Wc1  = (const float*)d_in[4];
    const float* bc1  = (const float*)d_in[5];
    const float* Wc2  = (const float*)d_in[6];
    const float* bc2  = (const float*)d_in[7];
    const float* Wc3  = (const float*)d_in[8];
    const float* bc3  = (const float*)d_in[9];
    const float* Wfc2 = (const float*)d_in[10];
    const float* bfc2 = (const float*)d_in[11];
    float* out = (float*)d_out;

    char* ws = (char*)d_ws;
    const size_t grow = (size_t)N_NODES * 32 * sizeof(__half);   // 6.4 MB
    size_t off = 0;
    __half* gA     = (__half*)(ws + off); off += grow;
    __half* gB     = (__half*)(ws + off); off += grow;
    int*   binned  = (int*)  (ws + off); off += (size_t)NBLK * CHUNK * sizeof(int);
    unsigned short* csr16 = (unsigned short*)(ws + off);
    off += ((size_t)N_EDGES + 8) * sizeof(unsigned short);
    float* dinv    = (float*)(ws + off); off += (size_t)N_NODES * sizeof(float);
    int*   rowseg  = (int*)  (ws + off); off += ((size_t)N_NODES * 4 + 16) * sizeof(int);
    int*   blkbin  = (int*)  (ws + off); off += (size_t)NBUCK * NBLK * sizeof(int);
    int*   locoff  = (int*)  (ws + off); off += (size_t)NBLK * NBUCK * sizeof(int);

    const int nb_f = (N_NODES * 4 + 255) / 256;       // 1563 (4 thr/node)

    k_binfill<<<NBLK, 256, 0, stream>>>(ei, binned, blkbin, locoff);
    k_sortdeg<<<NBUCK, 512, 0, stream>>>(binned, blkbin, locoff,
                                         x, Wfc1, bfc1, Wc1,
                                         csr16, rowseg, dinv, gA);

    k_gather_mid<<<nb_f, 256, 0, stream>>>(rowseg, csr16, gA, dinv, bc1, Wc2, gB);
    k_gather_mid<<<nb_f, 256, 0, stream>>>(rowseg, csr16, gB, dinv, bc2, Wc3, gA);
    k_gather_out<<<nb_f, 256, 0, stream>>>(rowseg, csr16, gA, dinv, bc3, Wfc2, bfc2, out);
}